// Round 1
// baseline (322.742 us; speedup 1.0000x reference)
//
#include <hip/hip_runtime.h>

#define HID 128
#define NPTS 32768
#define NIC  16384
#define GRID 256
#define BLK  512

__device__ __forceinline__ float tanh_fast(float x) {
    // 1 - 2/(e^{2x}+1); exact limits at +-inf, no branches
    float e = __expf(2.0f * x);
    return 1.0f - 2.0f / (e + 1.0f);
}

__device__ __forceinline__ float wave_allsum(float v) {
#pragma unroll
    for (int off = 32; off > 0; off >>= 1) v += __shfl_xor(v, off, 64);
    return v;
}

// stage a 128x128 fp32 weight matrix (64KB) global -> LDS, 512 threads
__device__ __forceinline__ void stage_w(float* dst, const float* __restrict__ src, int tid) {
    const float4* s4 = (const float4*)src;
    float4* d4 = (float4*)dst;
#pragma unroll
    for (int k = 0; k < 8; k++) d4[tid + k * BLK] = s4[tid + k * BLK];
}

// layer 0: input (x,y,t) -> 128 neurons. sSm layout: W0[3*128] at 0, B0[128] at 384.
// channels: 0=val 1=dx 2=dy 3=dt 4=dxx 5=dyy
template <int NCH, int P>
__device__ __forceinline__ void layer0(const float* sSm, const float* __restrict__ xg,
                                       int ptg0, float* sHw, int lane) {
    const int n0 = lane * 2;
#pragma unroll
    for (int p = 0; p < P; p++) {
        const float x = xg[(ptg0 + p) * 3 + 0];
        const float y = xg[(ptg0 + p) * 3 + 1];
        const float t = xg[(ptg0 + p) * 3 + 2];
        float* hp = &sHw[p * NCH * HID];
#pragma unroll
        for (int tt = 0; tt < 2; tt++) {
            const int n = n0 + tt;
            const float wx = sSm[n], wy = sSm[HID + n], wz = sSm[2 * HID + n];
            const float z = sSm[3 * HID + n] + wx * x + wy * y + wz * t;
            const float a = tanh_fast(z);
            if (NCH == 6) {
                const float s = 1.f - a * a;
                hp[0 * HID + n] = a;
                hp[1 * HID + n] = s * wx;
                hp[2 * HID + n] = s * wy;
                hp[3 * HID + n] = s * wz;
                hp[4 * HID + n] = -2.f * a * s * wx * wx;  // z_xx = 0
                hp[5 * HID + n] = -2.f * a * s * wy * wy;  // z_yy = 0
            } else {
                hp[n] = a;
            }
        }
    }
}

// one 128x128 hidden layer with tanh, propagating NCH dual channels, P points/wave.
// In-place on sHw: all LDS reads (whole wave, program order) precede the writes.
template <int NCH, int P>
__device__ __forceinline__ void hidden_layer(const float* sW, float* sHw,
                                             const float* sB, int lane) {
    const int n0 = lane * 2;
    float acc[P][NCH][2];
#pragma unroll
    for (int p = 0; p < P; p++)
#pragma unroll
        for (int c = 0; c < NCH; c++) { acc[p][c][0] = 0.f; acc[p][c][1] = 0.f; }

    for (int j = 0; j < HID; j += 4) {
        const float2 wa = *(const float2*)&sW[(j + 0) * HID + n0];
        const float2 wb = *(const float2*)&sW[(j + 1) * HID + n0];
        const float2 wc = *(const float2*)&sW[(j + 2) * HID + n0];
        const float2 wd = *(const float2*)&sW[(j + 3) * HID + n0];
#pragma unroll
        for (int p = 0; p < P; p++) {
#pragma unroll
            for (int c = 0; c < NCH; c++) {
                const float4 h = *(const float4*)&sHw[(p * NCH + c) * HID + j];
                acc[p][c][0] = fmaf(wa.x, h.x, fmaf(wb.x, h.y, fmaf(wc.x, h.z, fmaf(wd.x, h.w, acc[p][c][0]))));
                acc[p][c][1] = fmaf(wa.y, h.x, fmaf(wb.y, h.y, fmaf(wc.y, h.z, fmaf(wd.y, h.w, acc[p][c][1]))));
            }
        }
    }
    const float b0v = sB[n0], b1v = sB[n0 + 1];
#pragma unroll
    for (int p = 0; p < P; p++) {
        float* hp = &sHw[p * NCH * HID];
        const float z0 = acc[p][0][0] + b0v, z1 = acc[p][0][1] + b1v;
        const float a0 = tanh_fast(z0), a1 = tanh_fast(z1);
        if (NCH == 6) {
            const float s0 = 1.f - a0 * a0, s1 = 1.f - a1 * a1;
            *(float2*)&hp[0 * HID + n0] = make_float2(a0, a1);
            *(float2*)&hp[1 * HID + n0] = make_float2(s0 * acc[p][1][0], s1 * acc[p][1][1]);
            *(float2*)&hp[2 * HID + n0] = make_float2(s0 * acc[p][2][0], s1 * acc[p][2][1]);
            *(float2*)&hp[3 * HID + n0] = make_float2(s0 * acc[p][3][0], s1 * acc[p][3][1]);
            *(float2*)&hp[4 * HID + n0] = make_float2(
                s0 * acc[p][4][0] - 2.f * a0 * s0 * acc[p][1][0] * acc[p][1][0],
                s1 * acc[p][4][1] - 2.f * a1 * s1 * acc[p][1][1] * acc[p][1][1]);
            *(float2*)&hp[5 * HID + n0] = make_float2(
                s0 * acc[p][5][0] - 2.f * a0 * s0 * acc[p][2][0] * acc[p][2][0],
                s1 * acc[p][5][1] - 2.f * a1 * s1 * acc[p][2][1] * acc[p][2][1]);
        } else {
            *(float2*)&hp[n0] = make_float2(a0, a1);
        }
    }
}

// ---------------- n-net: mu = 0.01*n(x)^2, plus sum(mu^2) partials ----------------
__global__ __launch_bounds__(BLK) void k_mu(
    const float* __restrict__ xtr,
    const float* __restrict__ nw0, const float* __restrict__ nb0,
    const float* __restrict__ nw1, const float* __restrict__ nb1,
    const float* __restrict__ nw2, const float* __restrict__ nb2,
    const float* __restrict__ nw3, const float* __restrict__ nb3,
    float* __restrict__ muArr, float* __restrict__ muPart) {
    __shared__ __align__(16) float sW[HID * HID];
    __shared__ __align__(16) float sH[64 * HID];
    __shared__ __align__(16) float sSm[897];
    __shared__ float sRed[8];

    const int tid = threadIdx.x;
    const int lane = tid & 63;
    const int wv = tid >> 6;

    for (int i = tid; i < 384; i += BLK) sSm[i] = nw0[i];
    for (int i = tid; i < HID; i += BLK) {
        sSm[384 + i] = nb0[i];
        sSm[512 + i] = nb1[i];
        sSm[640 + i] = nb2[i];
        sSm[768 + i] = nw3[i];
    }
    if (tid == 0) sSm[896] = nb3[0];
    __syncthreads();

    float accMu2 = 0.f;

    for (int it = blockIdx.x; it < NPTS / 64; it += GRID) {
        const int ptg0 = it * 64 + wv * 8;
        float* sHw = &sH[(wv * 8) * HID];
        layer0<1, 8>(sSm, xtr, ptg0, sHw, lane);
        __syncthreads();
        stage_w(sW, nw1, tid);
        __syncthreads();
        hidden_layer<1, 8>(sW, sHw, &sSm[512], lane);
        __syncthreads();
        stage_w(sW, nw2, tid);
        __syncthreads();
        hidden_layer<1, 8>(sW, sHw, &sSm[640], lane);

#pragma unroll
        for (int p = 0; p < 8; p++) {
            float o = 0.f;
#pragma unroll
            for (int jj = 0; jj < 2; jj++) {
                const int j = lane + jj * 64;
                o = fmaf(sSm[768 + j], sHw[p * HID + j], o);
            }
            o = wave_allsum(o);
            o += sSm[896];
            const float muv = 0.01f * o * o;
            if (lane == 0) muArr[ptg0 + p] = muv;
            accMu2 += muv * muv;  // identical on all lanes; lane0's value used
        }
    }
    if (lane == 0) sRed[wv] = accMu2;
    __syncthreads();
    if (tid == 0) {
        float s = 0.f;
#pragma unroll
        for (int w = 0; w < 8; w++) s += sRed[w];
        muPart[blockIdx.x] = s;
    }
}

// ---------------- m-net with 6 dual channels -> PDE residual partials ----------------
__global__ __launch_bounds__(BLK) void k_residual(
    const float* __restrict__ xtr,
    const float* __restrict__ mw0, const float* __restrict__ mb0,
    const float* __restrict__ mw1, const float* __restrict__ mb1,
    const float* __restrict__ mw2, const float* __restrict__ mb2,
    const float* __restrict__ mw3, const float* __restrict__ mb3,
    const float* __restrict__ muArr, float* __restrict__ resPart) {
    __shared__ __align__(16) float sW[HID * HID];
    __shared__ __align__(16) float sH[16 * 6 * HID];
    __shared__ __align__(16) float sSm[1284];
    __shared__ float sRed[8][4];

    const int tid = threadIdx.x;
    const int lane = tid & 63;
    const int wv = tid >> 6;

    // sSm: W0:0(384) B0:384 B1:512 B2:640 W3:768(512) B3:1280(4)
    for (int i = tid; i < 384; i += BLK) sSm[i] = mw0[i];
    for (int i = tid; i < HID; i += BLK) {
        sSm[384 + i] = mb0[i];
        sSm[512 + i] = mb1[i];
        sSm[640 + i] = mb2[i];
    }
    for (int i = tid; i < 512; i += BLK) sSm[768 + i] = mw3[i];
    if (tid < 4) sSm[1280 + tid] = mb3[tid];
    __syncthreads();

    float racc[4] = {0.f, 0.f, 0.f, 0.f};

    for (int it = blockIdx.x; it < NPTS / 16; it += GRID) {
        const int ptg0 = it * 16 + wv * 2;
        float* sHw = &sH[(wv * 2) * 6 * HID];
        layer0<6, 2>(sSm, xtr, ptg0, sHw, lane);
        __syncthreads();  // all waves done with sW from previous iteration
        stage_w(sW, mw1, tid);
        __syncthreads();
        hidden_layer<6, 2>(sW, sHw, &sSm[512], lane);
        __syncthreads();
        stage_w(sW, mw2, tid);
        __syncthreads();
        hidden_layer<6, 2>(sW, sHw, &sSm[640], lane);

        // final linear layer (128->4, all 6 channels) + residual math
#pragma unroll
        for (int p = 0; p < 2; p++) {
            const float* hp = &sHw[p * 6 * HID];
            float oq[4][6];
#pragma unroll
            for (int k = 0; k < 4; k++)
#pragma unroll
                for (int c = 0; c < 6; c++) oq[k][c] = 0.f;
#pragma unroll
            for (int jj = 0; jj < 2; jj++) {
                const int j = lane + jj * 64;
                const float4 w3 = *(const float4*)&sSm[768 + j * 4];
#pragma unroll
                for (int c = 0; c < 6; c++) {
                    const float h = hp[c * HID + j];
                    oq[0][c] = fmaf(w3.x, h, oq[0][c]);
                    oq[1][c] = fmaf(w3.y, h, oq[1][c]);
                    oq[2][c] = fmaf(w3.z, h, oq[2][c]);
                    oq[3][c] = fmaf(w3.w, h, oq[3][c]);
                }
            }
#pragma unroll
            for (int k = 0; k < 4; k++)
#pragma unroll
                for (int c = 0; c < 6; c++) oq[k][c] = wave_allsum(oq[k][c]);
#pragma unroll
            for (int k = 0; k < 4; k++) oq[k][0] += sSm[1280 + k];

            const float rho = oq[0][0], rho_x = oq[0][1], rho_y = oq[0][2],
                        rho_t = oq[0][3], rho_xx = oq[0][4], rho_yy = oq[0][5];
            const float pr = oq[1][0], pr_x = oq[1][1], pr_y = oq[1][2],
                        pr_t = oq[1][3], pr_xx = oq[1][4], pr_yy = oq[1][5];
            const float u = oq[2][0], u_x = oq[2][1], u_y = oq[2][2],
                        u_t = oq[2][3], u_xx = oq[2][4], u_yy = oq[2][5];
            const float v = oq[3][0], v_x = oq[3][1], v_y = oq[3][2],
                        v_t = oq[3][3], v_xx = oq[3][4], v_yy = oq[3][5];

            const float ig1 = 2.5f;  // 1/(gamma-1)
            const float ke = 0.5f * (u * u + v * v);
            const float E = pr * ig1 + rho * ke;
            const float d_x = u * u_x + v * v_x;
            const float d_y = u * u_y + v * v_y;
            const float d_t = u * u_t + v * v_t;
            const float E_x = pr_x * ig1 + rho_x * ke + rho * d_x;
            const float E_y = pr_y * ig1 + rho_y * ke + rho * d_y;
            const float E_t = pr_t * ig1 + rho_t * ke + rho * d_t;
            const float E_xx = pr_xx * ig1 + rho_xx * ke + 2.f * rho_x * d_x +
                               rho * (u_x * u_x + u * u_xx + v_x * v_x + v * v_xx);
            const float E_yy = pr_yy * ig1 + rho_yy * ke + 2.f * rho_y * d_y +
                               rho * (u_y * u_y + u * u_yy + v_y * v_y + v * v_yy);

            const float m = muArr[ptg0 + p];

            const float r1 = rho_t + (rho_x * u + rho * u_x) + (rho_y * v + rho * v_y)
                           - m * (rho_xx + rho_yy);
            const float r2 = (rho_t * u + rho * u_t)
                           + (rho_x * u * u + 2.f * rho * u * u_x + pr_x)
                           + (rho_y * u * v + rho * u_y * v + rho * u * v_y)
                           - m * ((rho_xx * u + 2.f * rho_x * u_x + rho * u_xx)
                                + (rho_yy * u + 2.f * rho_y * u_y + rho * u_yy));
            const float r3 = (rho_t * v + rho * v_t)
                           + (rho_x * u * v + rho * u_x * v + rho * u * v_x)
                           + (rho_y * v * v + 2.f * rho * v * v_y + pr_y)
                           - m * ((rho_xx * v + 2.f * rho_x * v_x + rho * v_xx)
                                + (rho_yy * v + 2.f * rho_y * v_y + rho * v_yy));
            const float r4 = E_t
                           + (u_x * (E + pr) + u * (E_x + pr_x))
                           + (v_y * (E + pr) + v * (E_y + pr_y))
                           - m * (E_xx + E_yy);

            racc[0] += r1 * r1;
            racc[1] += r2 * r2;
            racc[2] += r3 * r3;
            racc[3] += r4 * r4;
        }
    }

    if (lane == 0) {
        sRed[wv][0] = racc[0]; sRed[wv][1] = racc[1];
        sRed[wv][2] = racc[2]; sRed[wv][3] = racc[3];
    }
    __syncthreads();
    if (tid == 0) {
        float s0 = 0, s1 = 0, s2 = 0, s3 = 0;
#pragma unroll
        for (int w = 0; w < 8; w++) {
            s0 += sRed[w][0]; s1 += sRed[w][1]; s2 += sRed[w][2]; s3 += sRed[w][3];
        }
        resPart[blockIdx.x * 4 + 0] = s0;
        resPart[blockIdx.x * 4 + 1] = s1;
        resPart[blockIdx.x * 4 + 2] = s2;
        resPart[blockIdx.x * 4 + 3] = s3;
    }
}

// ---------------- IC branch: m-net value-only on x_initial, quadrant sums ----------------
__global__ __launch_bounds__(BLK) void k_ic(
    const float* __restrict__ xin,
    const float* __restrict__ mw0, const float* __restrict__ mb0,
    const float* __restrict__ mw1, const float* __restrict__ mb1,
    const float* __restrict__ mw2, const float* __restrict__ mb2,
    const float* __restrict__ mw3, const float* __restrict__ mb3,
    const float* __restrict__ icg, float* __restrict__ icPart) {
    __shared__ __align__(16) float sW[HID * HID];
    __shared__ __align__(16) float sH[64 * HID];
    __shared__ __align__(16) float sSm[1284];
    __shared__ float sTq[16];
    __shared__ float sRed[8][8];

    const int tid = threadIdx.x;
    const int lane = tid & 63;
    const int wv = tid >> 6;

    for (int i = tid; i < 384; i += BLK) sSm[i] = mw0[i];
    for (int i = tid; i < HID; i += BLK) {
        sSm[384 + i] = mb0[i];
        sSm[512 + i] = mb1[i];
        sSm[640 + i] = mb2[i];
    }
    for (int i = tid; i < 512; i += BLK) sSm[768 + i] = mw3[i];
    if (tid < 4) sSm[1280 + tid] = mb3[tid];
    if (tid < 16) {
        // quad 0: xl&yt -> ic row 1; quad 1: xr&yt -> row 3;
        // quad 2: xl&yb -> row 0; quad 3: xr&yb -> row 2; perm = [0,3,1,2]
        const int k = tid & 3, q = tid >> 2;
        const int row = (q == 0) ? 1 : ((q == 1) ? 3 : ((q == 2) ? 0 : 2));
        const int pc = (k == 0) ? 0 : ((k == 1) ? 3 : ((k == 2) ? 1 : 2));
        sTq[q * 4 + k] = icg[row * 4 + pc];
    }
    __syncthreads();

    float qs[4] = {0, 0, 0, 0}, qc[4] = {0, 0, 0, 0};

    for (int it = blockIdx.x; it < NIC / 64; it += GRID) {
        const int ptg0 = it * 64 + wv * 8;
        float* sHw = &sH[(wv * 8) * HID];
        layer0<1, 8>(sSm, xin, ptg0, sHw, lane);
        __syncthreads();
        stage_w(sW, mw1, tid);
        __syncthreads();
        hidden_layer<1, 8>(sW, sHw, &sSm[512], lane);
        __syncthreads();
        stage_w(sW, mw2, tid);
        __syncthreads();
        hidden_layer<1, 8>(sW, sHw, &sSm[640], lane);

#pragma unroll
        for (int p = 0; p < 8; p++) {
            float o0 = 0, o1 = 0, o2 = 0, o3 = 0;
#pragma unroll
            for (int jj = 0; jj < 2; jj++) {
                const int j = lane + jj * 64;
                const float4 w3 = *(const float4*)&sSm[768 + j * 4];
                const float h = sHw[p * HID + j];
                o0 = fmaf(w3.x, h, o0);
                o1 = fmaf(w3.y, h, o1);
                o2 = fmaf(w3.z, h, o2);
                o3 = fmaf(w3.w, h, o3);
            }
            o0 = wave_allsum(o0); o1 = wave_allsum(o1);
            o2 = wave_allsum(o2); o3 = wave_allsum(o3);
            o0 += sSm[1280]; o1 += sSm[1281]; o2 += sSm[1282]; o3 += sSm[1283];

            const float x = xin[(ptg0 + p) * 3 + 0];
            const float y = xin[(ptg0 + p) * 3 + 1];
            int quad = -1;
            if (x < 0.5f && y > 0.5f) quad = 0;
            else if (x > 0.5f && y > 0.5f) quad = 1;
            else if (x < 0.5f && y < 0.5f) quad = 2;
            else if (x > 0.5f && y < 0.5f) quad = 3;
            if (quad >= 0) {  // wave-uniform branch
                const float d0 = o0 - sTq[quad * 4 + 0];
                const float d1 = o1 - sTq[quad * 4 + 1];
                const float d2 = o2 - sTq[quad * 4 + 2];
                const float d3 = o3 - sTq[quad * 4 + 3];
                const float ss = d0 * d0 + d1 * d1 + d2 * d2 + d3 * d3;
#pragma unroll
                for (int q = 0; q < 4; q++) {
                    qs[q] += (quad == q) ? ss : 0.f;
                    qc[q] += (quad == q) ? 1.f : 0.f;
                }
            }
        }
    }

    if (lane == 0) {
#pragma unroll
        for (int q = 0; q < 4; q++) { sRed[wv][q] = qs[q]; sRed[wv][4 + q] = qc[q]; }
    }
    __syncthreads();
    if (tid == 0) {
        float s[8] = {0, 0, 0, 0, 0, 0, 0, 0};
#pragma unroll
        for (int w = 0; w < 8; w++)
#pragma unroll
            for (int q = 0; q < 8; q++) s[q] += sRed[w][q];
#pragma unroll
        for (int q = 0; q < 8; q++) icPart[blockIdx.x * 8 + q] = s[q];
    }
}

// ---------------- finalize: deterministic fixed-order combine ----------------
__global__ void k_fin(const float* __restrict__ resPart, const float* __restrict__ muPart,
                      const float* __restrict__ icPart, float* __restrict__ out) {
    const int lane = threadIdx.x;  // 64 threads
    float r[4] = {0, 0, 0, 0};
    float m2 = 0.f;
    float qs[4] = {0, 0, 0, 0}, qc[4] = {0, 0, 0, 0};
    for (int b = lane; b < GRID; b += 64) {
#pragma unroll
        for (int i = 0; i < 4; i++) r[i] += resPart[b * 4 + i];
        m2 += muPart[b];
#pragma unroll
        for (int q = 0; q < 4; q++) {
            qs[q] += icPart[b * 8 + q];
            qc[q] += icPart[b * 8 + 4 + q];
        }
    }
#pragma unroll
    for (int i = 0; i < 4; i++) r[i] = wave_allsum(r[i]);
    m2 = wave_allsum(m2);
#pragma unroll
    for (int q = 0; q < 4; q++) { qs[q] = wave_allsum(qs[q]); qc[q] = wave_allsum(qc[q]); }
    if (lane == 0) {
        const float sumr = (r[0] + r[1] + r[2] + r[3]) / (float)NPTS;
        float init_loss = 0.f;
#pragma unroll
        for (int q = 0; q < 4; q++) init_loss += qs[q] / fmaxf(qc[q], 1.f);
        out[0] = sumr + 10.f * init_loss + 0.1f * (m2 / (float)NPTS);
    }
}

extern "C" void kernel_launch(void* const* d_in, const int* in_sizes, int n_in,
                              void* d_out, int out_size, void* d_ws, size_t ws_size,
                              hipStream_t stream) {
    const float* xtr = (const float*)d_in[0];
    const float* xin = (const float*)d_in[1];
    const float* icg = (const float*)d_in[2];
    const float* mw0 = (const float*)d_in[3];
    const float* mb0 = (const float*)d_in[4];
    const float* mw1 = (const float*)d_in[5];
    const float* mb1 = (const float*)d_in[6];
    const float* mw2 = (const float*)d_in[7];
    const float* mb2 = (const float*)d_in[8];
    const float* mw3 = (const float*)d_in[9];
    const float* mb3 = (const float*)d_in[10];
    const float* nw0 = (const float*)d_in[11];
    const float* nb0 = (const float*)d_in[12];
    const float* nw1 = (const float*)d_in[13];
    const float* nb1 = (const float*)d_in[14];
    const float* nw2 = (const float*)d_in[15];
    const float* nb2 = (const float*)d_in[16];
    const float* nw3 = (const float*)d_in[17];
    const float* nb3 = (const float*)d_in[18];

    float* wsf = (float*)d_ws;
    float* muArr = wsf;               // 32768
    float* resPart = wsf + 32768;     // 256*4
    float* muPart = wsf + 33792;      // 256
    float* icPart = wsf + 34048;      // 256*8

    k_mu<<<GRID, BLK, 0, stream>>>(xtr, nw0, nb0, nw1, nb1, nw2, nb2, nw3, nb3,
                                   muArr, muPart);
    k_residual<<<GRID, BLK, 0, stream>>>(xtr, mw0, mb0, mw1, mb1, mw2, mb2, mw3, mb3,
                                         muArr, resPart);
    k_ic<<<GRID, BLK, 0, stream>>>(xin, mw0, mb0, mw1, mb1, mw2, mb2, mw3, mb3,
                                   icg, icPart);
    k_fin<<<1, 64, 0, stream>>>(resPart, muPart, icPart, (float*)d_out);
}